// Round 4
// baseline (102.301 us; speedup 1.0000x reference)
//
#include <hip/hip_runtime.h>

#define B 4096
#define D 16
#define R 1024
#define NC 10
#define IC 170
#define NT 11
#define NP 176
#define BT 16              // samples per block
#define NBLK (B / BT)      // 256 blocks -> 1 per CU
#define ZSTR 136           // Zs row stride (ushorts): 272 B -> b128 reads 2-way (free)
#define FSTR 264           // fAs row stride (ushorts): 528 B -> b128 reads 2-way (free)
#define GSP 178            // Gs row stride (f32): 4*178 dw % 32 = 8 -> scalar writes 2-way

typedef __attribute__((ext_vector_type(8))) short short8;
typedef __attribute__((ext_vector_type(4))) float f32x4;

__device__ __forceinline__ unsigned short f2bf(float f) {
    unsigned u = __float_as_uint(f);
    return (unsigned short)((u + 0x7fffu + ((u >> 16) & 1u)) >> 16);  // RNE
}

// ---------------- K0: prep — convert_b (blocks 0..703) + indicator matrix
// Ind2[r][128] bf16 (blocks 704..707). Ind2[r][(d*4+m)*2 + e] = (rule_idx[d][r]==m)
// for e=0,1 (duplicated for the z_hi/z_lo interleave; K=128).
__global__ __launch_bounds__(256) void prep_kernel(
    const float* __restrict__ cons, unsigned short* __restrict__ Bsw,
    const int* __restrict__ rule_idx, unsigned short* __restrict__ Ind2)
{
    const int bid = blockIdx.x, tid = threadIdx.x;
    if (bid < 704) {
        // consequents fp32 [1024][170] -> Bsw bf16 [176][1024] (col-major per out col)
        int t = bid * 256 + tid;          // t < 176*1024
        int row = t >> 10;                // out col 0..175
        int k   = t & 1023;
        float v = (row < IC) ? cons[(size_t)k * IC + row] : 0.0f;
        Bsw[t] = f2bf(v);
    } else {
        int r = (bid - 704) * 256 + tid;  // rule id, coalesced over r per d
#pragma unroll
        for (int d = 0; d < D; ++d) {
            int mi = rule_idx[d * R + r];
            uint4 v;
            v.x = (mi == 0) ? 0x3F803F80u : 0u;
            v.y = (mi == 1) ? 0x3F803F80u : 0u;
            v.z = (mi == 2) ? 0x3F803F80u : 0u;
            v.w = (mi == 3) ? 0x3F803F80u : 0u;
            *(uint4*)&Ind2[(size_t)r * 128 + d * 8] = v;   // 16B store
        }
    }
}

// ---------------- K1: fused firing + yhat. 256 blocks x 16 samples, 4 waves.
// GEMM1 (16x1024x128, A=Z hi/lo bf16, B=Ind2) -> exp in regs -> per-wave fAs
// -> GEMM2 (16x176x256 per wave, K-quarter owned by the wave, B from L2) ->
// Gs epilogue with x_ext, direct y store. norm written from fp32 regs.
__global__ __launch_bounds__(256, 1) void fused_kernel(
    const float* __restrict__ x, const float* __restrict__ centers,
    const float* __restrict__ widths, const unsigned short* __restrict__ Ind2,
    const unsigned short* __restrict__ Bsw,
    float* __restrict__ out_y, float* __restrict__ out_norm,
    float* __restrict__ out_xext)
{
    __shared__ union U {
        struct {
            unsigned short Zs[BT * ZSTR];        // 4352 B  (16-aligned rows)
            unsigned short fAs[4][BT * FSTR];    // 33792 B (per-wave A tiles)
        } p1;
        float Gs[4][BT * GSP];                   // 45568 B (post-GEMM2 alias)
    } u;
    __shared__ float xe[BT * 17];
    __shared__ float s_red[4 * BT];

    const int tid = threadIdx.x;
    const int bl0 = blockIdx.x * BT;
    const int lane = tid & 63, wv = tid >> 6;
    const int m_ = lane & 15, q_ = lane >> 4;

    // x_ext (LDS + output) ---------------------------------------------------
    for (int t = tid; t < BT * 17; t += 256) {
        int bl = t / 17, i = t - bl * 17;
        float v = (i < 16) ? x[(size_t)(bl0 + bl) * D + i] : 1.0f;
        xe[t] = v;
        out_xext[(size_t)(bl0 + bl) * 17 + i] = v;
    }
    // Zs: z = 1e-9 - diff^2/(2 w^2), split hi/lo bf16 interleaved at k=2j,2j+1
    for (int p = tid; p < BT * 64; p += 256) {
        int s = p >> 6, j = p & 63;
        int d = j >> 2;
        float xv = x[(size_t)(bl0 + s) * D + d];
        float c = centers[j], w = widths[j];
        float diff = xv - c;
        float z = 1e-9f - diff * diff / (2.0f * w * w);
        unsigned short zh = f2bf(z);
        float zhf = __uint_as_float((unsigned)zh << 16);
        unsigned short zl = f2bf(z - zhf);
        *(unsigned*)&u.p1.Zs[s * ZSTR + 2 * j] = (unsigned)zh | ((unsigned)zl << 16);
    }
    __syncthreads();   // #1: Zs + xe ready

    // GEMM1: A = Zs[16][128], B = Ind2 rows (wave wv owns rules wv*256..+255)
    short8 za[4];
#pragma unroll
    for (int kh = 0; kh < 4; ++kh)
        za[kh] = *(const short8*)&u.p1.Zs[m_ * ZSTR + kh * 32 + q_ * 8];

    f32x4 acc1[16];
    const f32x4 zf = {0.f, 0.f, 0.f, 0.f};
#pragma unroll
    for (int nt = 0; nt < 16; ++nt) acc1[nt] = zf;

#pragma unroll
    for (int kh = 0; kh < 4; ++kh) {
#pragma unroll
        for (int nt = 0; nt < 16; ++nt) {
            int rule = (wv * 16 + nt) * 16 + m_;     // global rule of B-row
            short8 bf = *(const short8*)&Ind2[(size_t)rule * 128 + kh * 32 + q_ * 8];
            acc1[nt] = __builtin_amdgcn_mfma_f32_16x16x32_bf16(za[kh], bf, acc1[nt], 0, 0, 0);
        }
    }

    // exp + row-sum partials + write per-wave bf16 A tile (local rule = nt*16+m_)
    float f[16][4];
    float part[4] = {0.f, 0.f, 0.f, 0.f};
#pragma unroll
    for (int nt = 0; nt < 16; ++nt) {
#pragma unroll
        for (int r = 0; r < 4; ++r) {
            float v = __expf(acc1[nt][r]);           // sample = q_*4+r, D-layout
            f[nt][r] = v;
            part[r] += v;
            u.p1.fAs[wv][(q_ * 4 + r) * FSTR + nt * 16 + m_] = f2bf(v);
        }
    }
#pragma unroll
    for (int off = 1; off < 16; off <<= 1)
#pragma unroll
        for (int r = 0; r < 4; ++r) part[r] += __shfl_xor(part[r], off, 64);
    if (m_ == 0) {
#pragma unroll
        for (int r = 0; r < 4; ++r) s_red[wv * BT + q_ * 4 + r] = part[r];
    }
    __syncthreads();   // #2: fAs visible (also covers s_red)

    // GEMM2: A = fAs[wv] (K=256 local), B = Bsw cols from L2 (no block reuse)
    f32x4 acc2[11];
#pragma unroll
    for (int j = 0; j < 11; ++j) acc2[j] = zf;

#pragma unroll
    for (int kh = 0; kh < 8; ++kh) {
        short8 a = *(const short8*)&u.p1.fAs[wv][m_ * FSTR + kh * 32 + q_ * 8];
#pragma unroll
        for (int j = 0; j < 11; ++j) {
            int col = j * 16 + m_;
            short8 bf = *(const short8*)&Bsw[(size_t)col * R + wv * 256 + kh * 32 + q_ * 8];
            acc2[j] = __builtin_amdgcn_mfma_f32_16x16x32_bf16(a, bf, acc2[j], 0, 0, 0);
        }
    }
    __syncthreads();   // #3: all fAs/Zs reads done -> safe to alias Gs over p1

    // norm output: f * inv, fp32 from regs (s_red complete since #2)
    float invr[4];
#pragma unroll
    for (int r = 0; r < 4; ++r) {
        int s = q_ * 4 + r;
        invr[r] = 1.0f / (s_red[s] + s_red[16 + s] + s_red[32 + s] + s_red[48 + s] + 1e-9f);
    }
#pragma unroll
    for (int nt = 0; nt < 16; ++nt) {
        int rule = (wv * 16 + nt) * 16 + m_;
#pragma unroll
        for (int r = 0; r < 4; ++r)
            out_norm[(size_t)(bl0 + q_ * 4 + r) * R + rule] = f[nt][r] * invr[r];
    }

    // Gs: per-wave partial G[sample][col] (C/D: col=lane&15, row=q*4+reg)
#pragma unroll
    for (int j = 0; j < 11; ++j)
#pragma unroll
        for (int r = 0; r < 4; ++r)
            u.Gs[wv][(q_ * 4 + r) * GSP + j * 16 + m_] = acc2[j][r];
    __syncthreads();   // #4: Gs ready

    // y epilogue: contract with x_ext, scale by inv, direct store (no atomics)
    if (tid < BT * NC) {
        int bl = tid / NC, c = tid - bl * NC;
        float inv = 1.0f / (s_red[bl] + s_red[16 + bl] + s_red[32 + bl] + s_red[48 + bl] + 1e-9f);
        float y = 0.f;
#pragma unroll
        for (int i = 0; i < 17; ++i) {
            int gi = bl * GSP + i * NC + c;
            float g = u.Gs[0][gi] + u.Gs[1][gi] + u.Gs[2][gi] + u.Gs[3][gi];
            y += xe[bl * 17 + i] * g;
        }
        out_y[(size_t)(bl0 + bl) * NC + c] = y * inv;
    }
}

extern "C" void kernel_launch(void* const* d_in, const int* in_sizes, int n_in,
                              void* d_out, int out_size, void* d_ws, size_t ws_size,
                              hipStream_t stream) {
    const float* x        = (const float*)d_in[0];
    const float* centers  = (const float*)d_in[1];
    const float* widths   = (const float*)d_in[2];
    const float* cons     = (const float*)d_in[3];
    const int*   rule_idx = (const int*)d_in[4];

    float* out      = (float*)d_out;
    float* out_y    = out;                                  // (4096,10)
    float* out_norm = out + (size_t)B * NC;                 // (4096,1024)
    float* out_xext = out + (size_t)B * NC + (size_t)B * R; // (4096,17)

    unsigned short* Bsw  = (unsigned short*)d_ws;                        // 352 KB
    unsigned short* Ind2 = (unsigned short*)((char*)d_ws + 360448);      // 256 KB

    prep_kernel<<<708, 256, 0, stream>>>(cons, Bsw, rule_idx, Ind2);
    fused_kernel<<<NBLK, 256, 0, stream>>>(x, centers, widths, Ind2, Bsw,
                                           out_y, out_norm, out_xext);
}

// Round 5
// 93.790 us; speedup vs baseline: 1.0907x; 1.0907x over previous
//
#include <hip/hip_runtime.h>

#define B 4096
#define D 16
#define R 1024
#define NC 10
#define IC 170
#define NT 11
#define NP 176
#define KSPLIT 8
#define RPB (R / KSPLIT)   // 128 rules (K) per block — single LDS chunk
#define BT 64              // batch rows per yhat block
#define BSTR 136           // padded k-stride (bf16): 128+8 keeps b128 reads ~2-way
#define GSP 180            // Gs (epilogue) padded row stride
#define NAUX 864           // aux blocks in firing grid: 704 convert_b + 160 zero-y

typedef __attribute__((ext_vector_type(8))) short short8;
typedef __attribute__((ext_vector_type(4))) float f32x4;

__device__ __forceinline__ unsigned short f2bf(float f) {
    unsigned u = __float_as_uint(f);
    return (unsigned short)((u + 0x7fffu + ((u >> 16) & 1u)) >> 16);  // RNE
}

// ---------------- K1: firing + absorbed prep work.
// blocks 0..703   : consequents fp32 [1024][170] -> Bsw bf16 [176][1024]
// blocks 704..863 : zero out_y (needed by yhat atomics, next kernel)
// blocks 864..4959: firing for sample b = bid-864, rule pack inlined from
//                   rule_idx (64 KB, L2-broadcast) — no prep kernel needed.
__global__ __launch_bounds__(256) void firing_kernel(
    const float* __restrict__ x, const float* __restrict__ centers,
    const float* __restrict__ widths, const int* __restrict__ rule_idx,
    const float* __restrict__ cons, unsigned short* __restrict__ Bsw,
    float* __restrict__ out_norm, float* __restrict__ out_xext,
    float* __restrict__ out_y)
{
    const int bid = blockIdx.x, tid = threadIdx.x;
    if (bid < NAUX) {
        if (bid < 704) {
            int t = bid * 256 + tid;          // t < 176*1024
            int row = t >> 10;                // out col 0..175
            int k   = t & 1023;
            float v = (row < IC) ? cons[(size_t)k * IC + row] : 0.0f;
            Bsw[t] = f2bf(v);
        } else {
            out_y[(bid - 704) * 256 + tid] = 0.0f;
        }
        return;
    }
    const int b = bid - NAUX;

    __shared__ float s_z2[8][16];
    __shared__ float s_z4[4 * 256];
    __shared__ float s_red[4];
    const int lane = tid & 63, wv = tid >> 6;

    // inline rule pack: thread owns rules 4*tid..4*tid+3; 16 coalesced int4
    // loads over d, 2-bit packed word per rule (byte q = quad-table index).
    unsigned wq[4] = {0u, 0u, 0u, 0u};
#pragma unroll
    for (int d = 0; d < D; ++d) {
        int4 mi = *(const int4*)&rule_idx[d * R + 4 * tid];
        wq[0] |= (((unsigned)mi.x) & 3u) << (2 * d);
        wq[1] |= (((unsigned)mi.y) & 3u) << (2 * d);
        wq[2] |= (((unsigned)mi.z) & 3u) << (2 * d);
        wq[3] |= (((unsigned)mi.w) & 3u) << (2 * d);
    }

    // every wave computes z[0..63] redundantly: lane l holds z[l], l = d*4+m
    {
        int d = lane >> 2;
        float xv = x[b * D + d];
        float c = centers[lane], w = widths[lane];
        float diff = xv - c;
        float z = 1e-9f - diff * diff / (2.0f * w * w);

        if (tid < 17) out_xext[b * 17 + tid] = (tid < 16) ? x[b * D + tid] : 1.0f;

        // waves 0,1 build s_z2 (128 entries) via intra-wave shuffles of z
        if (wv < 2) {
            int p = tid >> 4, i = tid & 15;          // p in 0..7 across the 2 waves
            float za = __shfl(z, p * 8 + (i & 3), 64);
            float zb = __shfl(z, p * 8 + 4 + ((i >> 2) & 3), 64);
            s_z2[p][i] = za + zb;
        }
    }
    __syncthreads();
#pragma unroll
    for (int q = 0; q < 4; ++q)   // quad q = pairs (2q, 2q+1)
        s_z4[q * 256 + tid] = s_z2[2 * q][tid & 15] + s_z2[2 * q + 1][(tid >> 4) & 15];
    __syncthreads();

    float f[4], lsum = 0.0f;
#pragma unroll
    for (int k = 0; k < 4; ++k) {
        unsigned wk = wq[k];
        float s = s_z4[wk & 255] + s_z4[256 + ((wk >> 8) & 255)]
                + s_z4[512 + ((wk >> 16) & 255)] + s_z4[768 + (wk >> 24)];
        f[k] = __expf(s);
        lsum += f[k];
    }
#pragma unroll
    for (int off = 1; off < 64; off <<= 1) lsum += __shfl_xor(lsum, off, 64);
    if (lane == 0) s_red[wv] = lsum;
    __syncthreads();
    const float inv = 1.0f / (s_red[0] + s_red[1] + s_red[2] + s_red[3] + 1e-9f);
    float4 o;
    o.x = f[0] * inv; o.y = f[1] * inv; o.z = f[2] * inv; o.w = f[3] * inv;
    *(float4*)&out_norm[(size_t)b * R + 4 * tid] = o;
}

// ---------------- K2: MFMA GEMM (round-3 verified body). Block = 64 rows x
// 176 cols, K-slice of 128 rules (KSPLIT=8), single staging phase. 4 waves:
// wave w owns n-tiles [3w, 3w+ntn) x ALL 4 m-bands -> each b-frag ds_read
// feeds 4 MFMAs.
__global__ __launch_bounds__(256, 2) void yhat_kernel(
    const float* __restrict__ norm, const unsigned short* __restrict__ Bsw,
    const float* __restrict__ x, float* __restrict__ out_y)
{
    __shared__ unsigned short Bs[NP * BSTR];    // 47872 B (reused as Gs: 46080 B)
    __shared__ unsigned short As[BT * BSTR];    // 17408 B
    __shared__ float xe[BT * 17];               // 4352 B   (total 68 KB -> 2 blocks/CU)

    const int tid = threadIdx.x;
    const int mt = blockIdx.x & 63;
    const int ks = blockIdx.x >> 6;
    const int bl0 = mt * BT;
    const int kabs = ks * RPB;

    for (int t = tid; t < BT * 17; t += 256) {
        int bl = t / 17, i = t - bl * 17;
        xe[t] = (i < 16) ? x[(size_t)(bl0 + bl) * D + i] : 1.0f;
    }
    // stage B: 176 cols x 128 k (256 B each row) from pre-swizzled Bsw
    for (int t = tid; t < NP * 16; t += 256) {
        int row = t >> 4, seg = t & 15;
        *(short8*)&Bs[row * BSTR + seg * 8] =
            *(const short8*)&Bsw[row * R + kabs + seg * 8];
    }
    // stage A: 64 rows x 128 k, fp32 -> bf16 (2048 float4 loads, 8/thread)
    for (int t = tid; t < BT * 32; t += 256) {
        int row = t >> 5, c4 = t & 31;
        float4 v = *(const float4*)&norm[(size_t)(bl0 + row) * R + kabs + c4 * 4];
        ushort4 o;
        o.x = f2bf(v.x); o.y = f2bf(v.y); o.z = f2bf(v.z); o.w = f2bf(v.w);
        *(ushort4*)&As[row * BSTR + c4 * 4] = o;
    }
    __syncthreads();

    const int lane = tid & 63, wv = tid >> 6;
    const int m_ = lane & 15, q_ = lane >> 4;
    const int nt0 = wv * 3;
    const int ntn = (wv == 3) ? 2 : 3;

    f32x4 acc[4][3];
    const f32x4 zf = {0.f, 0.f, 0.f, 0.f};
#pragma unroll
    for (int mb = 0; mb < 4; ++mb)
#pragma unroll
        for (int j = 0; j < 3; ++j) acc[mb][j] = zf;

#pragma unroll
    for (int kh = 0; kh < 4; ++kh) {
        short8 a[4];
#pragma unroll
        for (int mb = 0; mb < 4; ++mb)
            a[mb] = *(const short8*)&As[(mb * 16 + m_) * BSTR + kh * 32 + q_ * 8];
#pragma unroll
        for (int j = 0; j < 3; ++j) {
            if (j < ntn) {
                short8 bfrag = *(const short8*)&Bs[((nt0 + j) * 16 + m_) * BSTR + kh * 32 + q_ * 8];
#pragma unroll
                for (int mb = 0; mb < 4; ++mb)
                    acc[mb][j] = __builtin_amdgcn_mfma_f32_16x16x32_bf16(a[mb], bfrag, acc[mb][j], 0, 0, 0);
            }
        }
    }

    __syncthreads();
    float* Gs = (float*)Bs;    // 64 x 180 fp32 = 46080 B <= sizeof(Bs)
#pragma unroll
    for (int j = 0; j < 3; ++j) {
        if (j < ntn) {
            int nt = nt0 + j;
#pragma unroll
            for (int mb = 0; mb < 4; ++mb)
#pragma unroll
                for (int r = 0; r < 4; ++r)
                    Gs[(mb * 16 + q_ * 4 + r) * GSP + nt * 16 + m_] = acc[mb][j][r];
        }
    }
    __syncthreads();
    for (int t = tid; t < BT * NC; t += 256) {
        int bl = t / NC, c = t - bl * NC;
        float y = 0.0f;
#pragma unroll
        for (int i = 0; i < 17; ++i)
            y += xe[bl * 17 + i] * Gs[bl * GSP + i * NC + c];
        atomicAdd(&out_y[(size_t)(bl0 + bl) * NC + c], y);
    }
}

extern "C" void kernel_launch(void* const* d_in, const int* in_sizes, int n_in,
                              void* d_out, int out_size, void* d_ws, size_t ws_size,
                              hipStream_t stream) {
    const float* x        = (const float*)d_in[0];
    const float* centers  = (const float*)d_in[1];
    const float* widths   = (const float*)d_in[2];
    const float* cons     = (const float*)d_in[3];
    const int*   rule_idx = (const int*)d_in[4];

    float* out      = (float*)d_out;
    float* out_y    = out;                                  // (4096,10)
    float* out_norm = out + (size_t)B * NC;                 // (4096,1024)
    float* out_xext = out + (size_t)B * NC + (size_t)B * R; // (4096,17)

    unsigned short* Bsw = (unsigned short*)d_ws;            // 352 KB

    firing_kernel<<<B + NAUX, 256, 0, stream>>>(x, centers, widths, rule_idx,
                                                cons, Bsw, out_norm, out_xext,
                                                out_y);
    yhat_kernel<<<(B / BT) * KSPLIT, 256, 0, stream>>>(out_norm, Bsw, x, out_y);
}

// Round 6
// 90.339 us; speedup vs baseline: 1.1324x; 1.0382x over previous
//
#include <hip/hip_runtime.h>

#define B 4096
#define D 16
#define R 1024
#define NC 10
#define IC 170
#define NT 11
#define NP 176
#define KSPLIT 8
#define RPB (R / KSPLIT)   // 128 rules (K) per block — single LDS chunk
#define BT 64              // batch rows per yhat block
#define BSTR 136           // padded k-stride (bf16): 128+8 keeps b128 reads ~2-way
#define GSP 180            // Gs (epilogue) padded row stride

typedef __attribute__((ext_vector_type(8))) short short8;
typedef __attribute__((ext_vector_type(4))) float f32x4;

__device__ __forceinline__ unsigned short f2bf(float f) {
    unsigned u = __float_as_uint(f);
    return (unsigned short)((u + 0x7fffu + ((u >> 16) & 1u)) >> 16);  // RNE
}

// ---------------- K0: fused prep — convert_b (blocks 0..703), pack_rules
// (704..707), zero out_y (708..867). All independent, one launch.
__global__ __launch_bounds__(256) void prep_kernel(
    const float* __restrict__ cons, unsigned short* __restrict__ Bsw,
    const int* __restrict__ rule_idx, unsigned* __restrict__ packed,
    float* __restrict__ out_y)
{
    const int bid = blockIdx.x, tid = threadIdx.x;
    if (bid < 704) {
        // consequents fp32 [1024][170] -> Bsw bf16 [176][1024] (col-major per out col)
        int t = bid * 256 + tid;          // t < 176*1024
        int row = t >> 10;                // out col 0..175
        int k   = t & 1023;
        float v = (row < IC) ? cons[(size_t)k * IC + row] : 0.0f;
        Bsw[t] = f2bf(v);
    } else if (bid < 708) {
        // pack rule_idx (16 dims x 2 bits); byte q = quad-table index for dims 4q..4q+3
        int r = (bid - 704) * 256 + tid;
        unsigned bits = 0;
#pragma unroll
        for (int d = 0; d < D; ++d)
            bits |= (((unsigned)rule_idx[d * R + r]) & 3u) << (2 * d);
        packed[r] = bits;
    } else {
        out_y[(bid - 708) * 256 + tid] = 0.0f;   // stream-ordered before yhat atomics
    }
}

// ---------------- K1: firing v4 — 2 samples/block, float2 (b64) quad tables.
// Each random gather ds_read_b64 serves BOTH samples: per-sample DS ops -45%,
// packed traffic halved, block count halved. Per-sample math identical to v3.
__global__ __launch_bounds__(256) void firing_kernel(
    const float* __restrict__ x, const float* __restrict__ centers,
    const float* __restrict__ widths, const unsigned* __restrict__ packed,
    float* __restrict__ out_norm, float* __restrict__ out_xext)
{
    __shared__ float2 s_z2[8][16];
    __shared__ float2 s_z4[4 * 256];
    __shared__ float2 s_red[4];
    const int tid = threadIdx.x;
    const int b0 = blockIdx.x * 2, b1 = b0 + 1;
    const int lane = tid & 63, wv = tid >> 6;

    // every wave computes z0/z1[0..63] redundantly: lane l holds z[l], l = d*4+m
    float z0, z1;
    {
        int d = lane >> 2;
        float c = centers[lane], w = widths[lane];
        float xv0 = x[(size_t)b0 * D + d];
        float xv1 = x[(size_t)b1 * D + d];
        float d0 = xv0 - c, d1 = xv1 - c;
        z0 = 1e-9f - d0 * d0 / (2.0f * w * w);
        z1 = 1e-9f - d1 * d1 / (2.0f * w * w);
    }
    if (tid < 34) {
        int si = tid / 17, i = tid - si * 17;
        int bb = b0 + si;
        out_xext[(size_t)bb * 17 + i] = (i < 16) ? x[(size_t)bb * D + i] : 1.0f;
    }
    // waves 0,1 build s_z2 (128 float2 entries) via intra-wave shuffles
    if (wv < 2) {
        int p = tid >> 4, i = tid & 15;          // p in 0..7 across the 2 waves
        int la = p * 8 + (i & 3);
        int lb = p * 8 + 4 + ((i >> 2) & 3);
        float za0 = __shfl(z0, la, 64), zb0 = __shfl(z0, lb, 64);
        float za1 = __shfl(z1, la, 64), zb1 = __shfl(z1, lb, 64);
        float2 v; v.x = za0 + zb0; v.y = za1 + zb1;
        s_z2[p][i] = v;
    }
    __syncthreads();
#pragma unroll
    for (int q = 0; q < 4; ++q) {  // quad q = pairs (2q, 2q+1)
        float2 a = s_z2[2 * q][tid & 15];
        float2 c = s_z2[2 * q + 1][(tid >> 4) & 15];
        float2 v; v.x = a.x + c.x; v.y = a.y + c.y;
        s_z4[q * 256 + tid] = v;
    }
    __syncthreads();

    // thread handles 4 contiguous rules for both samples: b64 gathers
    uint4 pw = *(const uint4*)&packed[4 * tid];
    unsigned wq[4] = {pw.x, pw.y, pw.z, pw.w};
    float f0[4], f1[4], l0 = 0.0f, l1 = 0.0f;
#pragma unroll
    for (int k = 0; k < 4; ++k) {
        unsigned wk = wq[k];
        float2 g0 = s_z4[wk & 255];
        float2 g1 = s_z4[256 + ((wk >> 8) & 255)];
        float2 g2 = s_z4[512 + ((wk >> 16) & 255)];
        float2 g3 = s_z4[768 + (wk >> 24)];
        float s0 = g0.x + g1.x + g2.x + g3.x;
        float s1 = g0.y + g1.y + g2.y + g3.y;
        f0[k] = __expf(s0);
        f1[k] = __expf(s1);
        l0 += f0[k];
        l1 += f1[k];
    }
#pragma unroll
    for (int off = 1; off < 64; off <<= 1) {
        l0 += __shfl_xor(l0, off, 64);
        l1 += __shfl_xor(l1, off, 64);
    }
    if (lane == 0) { float2 v; v.x = l0; v.y = l1; s_red[wv] = v; }
    __syncthreads();
    const float inv0 = 1.0f / (s_red[0].x + s_red[1].x + s_red[2].x + s_red[3].x + 1e-9f);
    const float inv1 = 1.0f / (s_red[0].y + s_red[1].y + s_red[2].y + s_red[3].y + 1e-9f);
    float4 o0, o1;
    o0.x = f0[0] * inv0; o0.y = f0[1] * inv0; o0.z = f0[2] * inv0; o0.w = f0[3] * inv0;
    o1.x = f1[0] * inv1; o1.y = f1[1] * inv1; o1.z = f1[2] * inv1; o1.w = f1[3] * inv1;
    *(float4*)&out_norm[(size_t)b0 * R + 4 * tid] = o0;
    *(float4*)&out_norm[(size_t)b1 * R + 4 * tid] = o1;
}

// ---------------- K2: MFMA GEMM (round-3 verified body). Block = 64 rows x
// 176 cols, K-slice of 128 rules (KSPLIT=8), single staging phase. 4 waves:
// wave w owns n-tiles [3w, 3w+ntn) x ALL 4 m-bands -> each b-frag ds_read
// feeds 4 MFMAs.
__global__ __launch_bounds__(256, 2) void yhat_kernel(
    const float* __restrict__ norm, const unsigned short* __restrict__ Bsw,
    const float* __restrict__ x, float* __restrict__ out_y)
{
    __shared__ unsigned short Bs[NP * BSTR];    // 47872 B (reused as Gs: 46080 B)
    __shared__ unsigned short As[BT * BSTR];    // 17408 B
    __shared__ float xe[BT * 17];               // 4352 B   (total 68 KB -> 2 blocks/CU)

    const int tid = threadIdx.x;
    const int mt = blockIdx.x & 63;
    const int ks = blockIdx.x >> 6;
    const int bl0 = mt * BT;
    const int kabs = ks * RPB;

    for (int t = tid; t < BT * 17; t += 256) {
        int bl = t / 17, i = t - bl * 17;
        xe[t] = (i < 16) ? x[(size_t)(bl0 + bl) * D + i] : 1.0f;
    }
    // stage B: 176 cols x 128 k (256 B each row) from pre-swizzled Bsw
    for (int t = tid; t < NP * 16; t += 256) {
        int row = t >> 4, seg = t & 15;
        *(short8*)&Bs[row * BSTR + seg * 8] =
            *(const short8*)&Bsw[row * R + kabs + seg * 8];
    }
    // stage A: 64 rows x 128 k, fp32 -> bf16 (2048 float4 loads, 8/thread)
    for (int t = tid; t < BT * 32; t += 256) {
        int row = t >> 5, c4 = t & 31;
        float4 v = *(const float4*)&norm[(size_t)(bl0 + row) * R + kabs + c4 * 4];
        ushort4 o;
        o.x = f2bf(v.x); o.y = f2bf(v.y); o.z = f2bf(v.z); o.w = f2bf(v.w);
        *(ushort4*)&As[row * BSTR + c4 * 4] = o;
    }
    __syncthreads();

    const int lane = tid & 63, wv = tid >> 6;
    const int m_ = lane & 15, q_ = lane >> 4;
    const int nt0 = wv * 3;
    const int ntn = (wv == 3) ? 2 : 3;

    f32x4 acc[4][3];
    const f32x4 zf = {0.f, 0.f, 0.f, 0.f};
#pragma unroll
    for (int mb = 0; mb < 4; ++mb)
#pragma unroll
        for (int j = 0; j < 3; ++j) acc[mb][j] = zf;

#pragma unroll
    for (int kh = 0; kh < 4; ++kh) {
        short8 a[4];
#pragma unroll
        for (int mb = 0; mb < 4; ++mb)
            a[mb] = *(const short8*)&As[(mb * 16 + m_) * BSTR + kh * 32 + q_ * 8];
#pragma unroll
        for (int j = 0; j < 3; ++j) {
            if (j < ntn) {
                short8 bfrag = *(const short8*)&Bs[((nt0 + j) * 16 + m_) * BSTR + kh * 32 + q_ * 8];
#pragma unroll
                for (int mb = 0; mb < 4; ++mb)
                    acc[mb][j] = __builtin_amdgcn_mfma_f32_16x16x32_bf16(a[mb], bfrag, acc[mb][j], 0, 0, 0);
            }
        }
    }

    __syncthreads();
    float* Gs = (float*)Bs;    // 64 x 180 fp32 = 46080 B <= sizeof(Bs)
#pragma unroll
    for (int j = 0; j < 3; ++j) {
        if (j < ntn) {
            int nt = nt0 + j;
#pragma unroll
            for (int mb = 0; mb < 4; ++mb)
#pragma unroll
                for (int r = 0; r < 4; ++r)
                    Gs[(mb * 16 + q_ * 4 + r) * GSP + nt * 16 + m_] = acc[mb][j][r];
        }
    }
    __syncthreads();
    for (int t = tid; t < BT * NC; t += 256) {
        int bl = t / NC, c = t - bl * NC;
        float y = 0.0f;
#pragma unroll
        for (int i = 0; i < 17; ++i)
            y += xe[bl * 17 + i] * Gs[bl * GSP + i * NC + c];
        atomicAdd(&out_y[(size_t)(bl0 + bl) * NC + c], y);
    }
}

extern "C" void kernel_launch(void* const* d_in, const int* in_sizes, int n_in,
                              void* d_out, int out_size, void* d_ws, size_t ws_size,
                              hipStream_t stream) {
    const float* x        = (const float*)d_in[0];
    const float* centers  = (const float*)d_in[1];
    const float* widths   = (const float*)d_in[2];
    const float* cons     = (const float*)d_in[3];
    const int*   rule_idx = (const int*)d_in[4];

    float* out      = (float*)d_out;
    float* out_y    = out;                                  // (4096,10)
    float* out_norm = out + (size_t)B * NC;                 // (4096,1024)
    float* out_xext = out + (size_t)B * NC + (size_t)B * R; // (4096,17)

    unsigned* packed     = (unsigned*)d_ws;                          // 4 KB
    unsigned short* Bsw  = (unsigned short*)((char*)d_ws + 4096);    // 352 KB

    prep_kernel<<<868, 256, 0, stream>>>(cons, Bsw, rule_idx, packed, out_y);
    firing_kernel<<<B / 2, 256, 0, stream>>>(x, centers, widths, packed,
                                             out_norm, out_xext);
    yhat_kernel<<<(B / BT) * KSPLIT, 256, 0, stream>>>(out_norm, Bsw, x, out_y);
}

// Round 7
// 87.258 us; speedup vs baseline: 1.1724x; 1.0353x over previous
//
#include <hip/hip_runtime.h>

#define B 4096
#define D 16
#define R 1024
#define NC 10
#define IC 170
#define NT 11
#define NP 176
#define KSPLIT 8
#define RPB (R / KSPLIT)   // 128 rules (K) per block — single LDS chunk
#define BT 64              // batch rows per yhat block
#define BSTR 136           // padded k-stride (bf16): 128+8 keeps b128 reads ~2-way
#define GSP 180            // Gs (epilogue) padded row stride

typedef __attribute__((ext_vector_type(8))) short short8;
typedef __attribute__((ext_vector_type(4))) float f32x4;

__device__ __forceinline__ unsigned short f2bf(float f) {
    unsigned u = __float_as_uint(f);
    return (unsigned short)((u + 0x7fffu + ((u >> 16) & 1u)) >> 16);  // RNE
}

// ---------------- K0: fused prep — convert_b (blocks 0..703), pack_rules
// (704..707), zero out_y (708..867). All independent, one launch.
__global__ __launch_bounds__(256) void prep_kernel(
    const float* __restrict__ cons, unsigned short* __restrict__ Bsw,
    const int* __restrict__ rule_idx, unsigned* __restrict__ packed,
    float* __restrict__ out_y)
{
    const int bid = blockIdx.x, tid = threadIdx.x;
    if (bid < 704) {
        // consequents fp32 [1024][170] -> Bsw bf16 [176][1024] (col-major per out col)
        int t = bid * 256 + tid;          // t < 176*1024
        int row = t >> 10;                // out col 0..175
        int k   = t & 1023;
        float v = (row < IC) ? cons[(size_t)k * IC + row] : 0.0f;
        Bsw[t] = f2bf(v);
    } else if (bid < 708) {
        // pack rule_idx (16 dims x 2 bits); byte q = quad-table index for dims 4q..4q+3
        int r = (bid - 704) * 256 + tid;
        unsigned bits = 0;
#pragma unroll
        for (int d = 0; d < D; ++d)
            bits |= (((unsigned)rule_idx[d * R + r]) & 3u) << (2 * d);
        packed[r] = bits;
    } else {
        out_y[(bid - 708) * 256 + tid] = 0.0f;   // stream-ordered before yhat atomics
    }
}

// ---------------- K1: firing v4 — 2 samples/block, float2 (b64) quad tables.
// v5: additionally emits bf16 norm copy (norm_b16) when provided, so yhat
// can consume A-fragments directly from L2 (values bit-identical to the
// f2bf(norm) yhat used to compute itself).
__global__ __launch_bounds__(256) void firing_kernel(
    const float* __restrict__ x, const float* __restrict__ centers,
    const float* __restrict__ widths, const unsigned* __restrict__ packed,
    float* __restrict__ out_norm, float* __restrict__ out_xext,
    unsigned short* __restrict__ norm_b16)
{
    __shared__ float2 s_z2[8][16];
    __shared__ float2 s_z4[4 * 256];
    __shared__ float2 s_red[4];
    const int tid = threadIdx.x;
    const int b0 = blockIdx.x * 2, b1 = b0 + 1;
    const int lane = tid & 63, wv = tid >> 6;

    // every wave computes z0/z1[0..63] redundantly: lane l holds z[l], l = d*4+m
    float z0, z1;
    {
        int d = lane >> 2;
        float c = centers[lane], w = widths[lane];
        float xv0 = x[(size_t)b0 * D + d];
        float xv1 = x[(size_t)b1 * D + d];
        float d0 = xv0 - c, d1 = xv1 - c;
        z0 = 1e-9f - d0 * d0 / (2.0f * w * w);
        z1 = 1e-9f - d1 * d1 / (2.0f * w * w);
    }
    if (tid < 34) {
        int si = tid / 17, i = tid - si * 17;
        int bb = b0 + si;
        out_xext[(size_t)bb * 17 + i] = (i < 16) ? x[(size_t)bb * D + i] : 1.0f;
    }
    // waves 0,1 build s_z2 (128 float2 entries) via intra-wave shuffles
    if (wv < 2) {
        int p = tid >> 4, i = tid & 15;          // p in 0..7 across the 2 waves
        int la = p * 8 + (i & 3);
        int lb = p * 8 + 4 + ((i >> 2) & 3);
        float za0 = __shfl(z0, la, 64), zb0 = __shfl(z0, lb, 64);
        float za1 = __shfl(z1, la, 64), zb1 = __shfl(z1, lb, 64);
        float2 v; v.x = za0 + zb0; v.y = za1 + zb1;
        s_z2[p][i] = v;
    }
    __syncthreads();
#pragma unroll
    for (int q = 0; q < 4; ++q) {  // quad q = pairs (2q, 2q+1)
        float2 a = s_z2[2 * q][tid & 15];
        float2 c = s_z2[2 * q + 1][(tid >> 4) & 15];
        float2 v; v.x = a.x + c.x; v.y = a.y + c.y;
        s_z4[q * 256 + tid] = v;
    }
    __syncthreads();

    // thread handles 4 contiguous rules for both samples: b64 gathers
    uint4 pw = *(const uint4*)&packed[4 * tid];
    unsigned wq[4] = {pw.x, pw.y, pw.z, pw.w};
    float f0[4], f1[4], l0 = 0.0f, l1 = 0.0f;
#pragma unroll
    for (int k = 0; k < 4; ++k) {
        unsigned wk = wq[k];
        float2 g0 = s_z4[wk & 255];
        float2 g1 = s_z4[256 + ((wk >> 8) & 255)];
        float2 g2 = s_z4[512 + ((wk >> 16) & 255)];
        float2 g3 = s_z4[768 + (wk >> 24)];
        float s0 = g0.x + g1.x + g2.x + g3.x;
        float s1 = g0.y + g1.y + g2.y + g3.y;
        f0[k] = __expf(s0);
        f1[k] = __expf(s1);
        l0 += f0[k];
        l1 += f1[k];
    }
#pragma unroll
    for (int off = 1; off < 64; off <<= 1) {
        l0 += __shfl_xor(l0, off, 64);
        l1 += __shfl_xor(l1, off, 64);
    }
    if (lane == 0) { float2 v; v.x = l0; v.y = l1; s_red[wv] = v; }
    __syncthreads();
    const float inv0 = 1.0f / (s_red[0].x + s_red[1].x + s_red[2].x + s_red[3].x + 1e-9f);
    const float inv1 = 1.0f / (s_red[0].y + s_red[1].y + s_red[2].y + s_red[3].y + 1e-9f);
    float4 o0, o1;
    o0.x = f0[0] * inv0; o0.y = f0[1] * inv0; o0.z = f0[2] * inv0; o0.w = f0[3] * inv0;
    o1.x = f1[0] * inv1; o1.y = f1[1] * inv1; o1.z = f1[2] * inv1; o1.w = f1[3] * inv1;
    *(float4*)&out_norm[(size_t)b0 * R + 4 * tid] = o0;
    *(float4*)&out_norm[(size_t)b1 * R + 4 * tid] = o1;
    if (norm_b16) {   // uniform branch
        ushort4 h0, h1;
        h0.x = f2bf(o0.x); h0.y = f2bf(o0.y); h0.z = f2bf(o0.z); h0.w = f2bf(o0.w);
        h1.x = f2bf(o1.x); h1.y = f2bf(o1.y); h1.z = f2bf(o1.z); h1.w = f2bf(o1.w);
        *(ushort4*)&norm_b16[(size_t)b0 * R + 4 * tid] = h0;
        *(ushort4*)&norm_b16[(size_t)b1 * R + 4 * tid] = h1;
    }
}

// ---------------- K2a: MFMA GEMM v2 — no As LDS. A-fragments come straight
// from bf16 norm in L2 (16 short8 loads/thread; x4-wave amplification = 33 MB
// L2, ~1 us, hidden by TLP). LDS 52.2 KB -> 3 blocks/CU. B staging unchanged.
__global__ __launch_bounds__(256, 3) void yhat_kernel2(
    const unsigned short* __restrict__ normb, const unsigned short* __restrict__ Bsw,
    const float* __restrict__ x, float* __restrict__ out_y)
{
    __shared__ unsigned short Bs[NP * BSTR];    // 47872 B (reused as Gs: 46080 B)
    __shared__ float xe[BT * 17];               // 4352 B   (total 52224 B)

    const int tid = threadIdx.x;
    const int mt = blockIdx.x & 63;
    const int ks = blockIdx.x >> 6;
    const int bl0 = mt * BT;
    const int kabs = ks * RPB;

    for (int t = tid; t < BT * 17; t += 256) {
        int bl = t / 17, i = t - bl * 17;
        xe[t] = (i < 16) ? x[(size_t)(bl0 + bl) * D + i] : 1.0f;
    }
    // stage B: 176 cols x 128 k (256 B each row) from pre-swizzled Bsw
    for (int t = tid; t < NP * 16; t += 256) {
        int row = t >> 4, seg = t & 15;
        *(short8*)&Bs[row * BSTR + seg * 8] =
            *(const short8*)&Bsw[row * R + kabs + seg * 8];
    }
    __syncthreads();

    const int lane = tid & 63, wv = tid >> 6;
    const int m_ = lane & 15, q_ = lane >> 4;
    const int nt0 = wv * 3;
    const int ntn = (wv == 3) ? 2 : 3;

    f32x4 acc[4][3];
    const f32x4 zf = {0.f, 0.f, 0.f, 0.f};
#pragma unroll
    for (int mb = 0; mb < 4; ++mb)
#pragma unroll
        for (int j = 0; j < 3; ++j) acc[mb][j] = zf;

#pragma unroll
    for (int kh = 0; kh < 4; ++kh) {
        short8 a[4];
#pragma unroll
        for (int mb = 0; mb < 4; ++mb)
            a[mb] = *(const short8*)&normb[(size_t)(bl0 + mb * 16 + m_) * R
                                           + kabs + kh * 32 + q_ * 8];
#pragma unroll
        for (int j = 0; j < 3; ++j) {
            if (j < ntn) {
                short8 bfrag = *(const short8*)&Bs[((nt0 + j) * 16 + m_) * BSTR + kh * 32 + q_ * 8];
#pragma unroll
                for (int mb = 0; mb < 4; ++mb)
                    acc[mb][j] = __builtin_amdgcn_mfma_f32_16x16x32_bf16(a[mb], bfrag, acc[mb][j], 0, 0, 0);
            }
        }
    }

    __syncthreads();
    float* Gs = (float*)Bs;    // 64 x 180 fp32 = 46080 B <= sizeof(Bs)
#pragma unroll
    for (int j = 0; j < 3; ++j) {
        if (j < ntn) {
            int nt = nt0 + j;
#pragma unroll
            for (int mb = 0; mb < 4; ++mb)
#pragma unroll
                for (int r = 0; r < 4; ++r)
                    Gs[(mb * 16 + q_ * 4 + r) * GSP + nt * 16 + m_] = acc[mb][j][r];
        }
    }
    __syncthreads();
    for (int t = tid; t < BT * NC; t += 256) {
        int bl = t / NC, c = t - bl * NC;
        float y = 0.0f;
#pragma unroll
        for (int i = 0; i < 17; ++i)
            y += xe[bl * 17 + i] * Gs[bl * GSP + i * NC + c];
        atomicAdd(&out_y[(size_t)(bl0 + bl) * NC + c], y);
    }
}

// ---------------- K2b: fallback — exact round-6 verified yhat (LDS As path),
// used only if ws is too small for norm_b16.
__global__ __launch_bounds__(256, 2) void yhat_kernel(
    const float* __restrict__ norm, const unsigned short* __restrict__ Bsw,
    const float* __restrict__ x, float* __restrict__ out_y)
{
    __shared__ unsigned short Bs[NP * BSTR];
    __shared__ unsigned short As[BT * BSTR];
    __shared__ float xe[BT * 17];

    const int tid = threadIdx.x;
    const int mt = blockIdx.x & 63;
    const int ks = blockIdx.x >> 6;
    const int bl0 = mt * BT;
    const int kabs = ks * RPB;

    for (int t = tid; t < BT * 17; t += 256) {
        int bl = t / 17, i = t - bl * 17;
        xe[t] = (i < 16) ? x[(size_t)(bl0 + bl) * D + i] : 1.0f;
    }
    for (int t = tid; t < NP * 16; t += 256) {
        int row = t >> 4, seg = t & 15;
        *(short8*)&Bs[row * BSTR + seg * 8] =
            *(const short8*)&Bsw[row * R + kabs + seg * 8];
    }
    for (int t = tid; t < BT * 32; t += 256) {
        int row = t >> 5, c4 = t & 31;
        float4 v = *(const float4*)&norm[(size_t)(bl0 + row) * R + kabs + c4 * 4];
        ushort4 o;
        o.x = f2bf(v.x); o.y = f2bf(v.y); o.z = f2bf(v.z); o.w = f2bf(v.w);
        *(ushort4*)&As[row * BSTR + c4 * 4] = o;
    }
    __syncthreads();

    const int lane = tid & 63, wv = tid >> 6;
    const int m_ = lane & 15, q_ = lane >> 4;
    const int nt0 = wv * 3;
    const int ntn = (wv == 3) ? 2 : 3;

    f32x4 acc[4][3];
    const f32x4 zf = {0.f, 0.f, 0.f, 0.f};
#pragma unroll
    for (int mb = 0; mb < 4; ++mb)
#pragma unroll
        for (int j = 0; j < 3; ++j) acc[mb][j] = zf;

#pragma unroll
    for (int kh = 0; kh < 4; ++kh) {
        short8 a[4];
#pragma unroll
        for (int mb = 0; mb < 4; ++mb)
            a[mb] = *(const short8*)&As[(mb * 16 + m_) * BSTR + kh * 32 + q_ * 8];
#pragma unroll
        for (int j = 0; j < 3; ++j) {
            if (j < ntn) {
                short8 bfrag = *(const short8*)&Bs[((nt0 + j) * 16 + m_) * BSTR + kh * 32 + q_ * 8];
#pragma unroll
                for (int mb = 0; mb < 4; ++mb)
                    acc[mb][j] = __builtin_amdgcn_mfma_f32_16x16x32_bf16(a[mb], bfrag, acc[mb][j], 0, 0, 0);
            }
        }
    }

    __syncthreads();
    float* Gs = (float*)Bs;
#pragma unroll
    for (int j = 0; j < 3; ++j) {
        if (j < ntn) {
            int nt = nt0 + j;
#pragma unroll
            for (int mb = 0; mb < 4; ++mb)
#pragma unroll
                for (int r = 0; r < 4; ++r)
                    Gs[(mb * 16 + q_ * 4 + r) * GSP + nt * 16 + m_] = acc[mb][j][r];
        }
    }
    __syncthreads();
    for (int t = tid; t < BT * NC; t += 256) {
        int bl = t / NC, c = t - bl * NC;
        float y = 0.0f;
#pragma unroll
        for (int i = 0; i < 17; ++i)
            y += xe[bl * 17 + i] * Gs[bl * GSP + i * NC + c];
        atomicAdd(&out_y[(size_t)(bl0 + bl) * NC + c], y);
    }
}

extern "C" void kernel_launch(void* const* d_in, const int* in_sizes, int n_in,
                              void* d_out, int out_size, void* d_ws, size_t ws_size,
                              hipStream_t stream) {
    const float* x        = (const float*)d_in[0];
    const float* centers  = (const float*)d_in[1];
    const float* widths   = (const float*)d_in[2];
    const float* cons     = (const float*)d_in[3];
    const int*   rule_idx = (const int*)d_in[4];

    float* out      = (float*)d_out;
    float* out_y    = out;                                  // (4096,10)
    float* out_norm = out + (size_t)B * NC;                 // (4096,1024)
    float* out_xext = out + (size_t)B * NC + (size_t)B * R; // (4096,17)

    unsigned* packed     = (unsigned*)d_ws;                          // 4 KB
    unsigned short* Bsw  = (unsigned short*)((char*)d_ws + 4096);    // 352 KB
    const size_t NB16_OFF = 4096 + 360448;                           // 364544 (64-aligned)
    const size_t need = NB16_OFF + (size_t)B * R * 2;                // ~8.75 MB
    unsigned short* normb = (ws_size >= need)
        ? (unsigned short*)((char*)d_ws + NB16_OFF) : nullptr;

    prep_kernel<<<868, 256, 0, stream>>>(cons, Bsw, rule_idx, packed, out_y);
    firing_kernel<<<B / 2, 256, 0, stream>>>(x, centers, widths, packed,
                                             out_norm, out_xext, normb);
    if (normb)
        yhat_kernel2<<<(B / BT) * KSPLIT, 256, 0, stream>>>(normb, Bsw, x, out_y);
    else
        yhat_kernel<<<(B / BT) * KSPLIT, 256, 0, stream>>>(out_norm, Bsw, x, out_y);
}